// Round 15
// baseline (1539.750 us; speedup 1.0000x reference)
//
#include <hip/hip_runtime.h>

#define B_N 16
#define T_N 15
#define CIN 64
#define COUT 128
#define HS 56
#define HWN 3136
#define NSG (16 * 128 * 28 * 28)
#define XSW 12               // padded LDS row stride: (lh*12+lw)%32 => exact 2-way
#define XSC 120              // floats per ci plane (10 rows x stride 12)

// PROVEN reference model (R10/R14, absmax=0.0):
//   conv: per-output flat sequential FMA chain, k-order (kh, kw, ci-innermost),
//         bias as separate rounded add. fma(+/-0,w,acc)==acc bit-exact.
//   elementwise/scan: per-op rounding, no FMA.
// R14 structure (lane=pixel, wave=co16, SGPR weights) kept; this round only:
//   - xs row stride 10 -> 12 (bank-conflict-free 2-way)
//   - ci unroll x4 (latency hiding)

// ---------- weight transpose: w[co][ci][kh][kw] -> wt4[tap][ci][co]
__global__ void wt_kernel(const float* __restrict__ w, float* __restrict__ wt4) {
    int i = blockIdx.x * 256 + threadIdx.x;  // 0 .. 73727
    if (i >= COUT * 576) return;
    int co = i / 576;
    int r = i - co * 576;      // ci*9 + kh*3 + kw
    int ci = r / 9;
    int kk = r - ci * 9;       // kh*3+kw
    wt4[((size_t)kk * CIN + ci) * COUT + co] = w[i];
}

// ---------- conv: 8 waves x (64 px lanes x 16 co acc), weights in SGPR ----
__global__ __launch_bounds__(512) void conv_sgpr(
    const float* __restrict__ x, const float* __restrict__ wt4,
    const float* __restrict__ bias, float* __restrict__ obuf,
    int t0, int nz)
{
    __shared__ float xs[CIN * XSC];   // [ci][10][stride 12], zero halo

    // XCD-chunked swizzle (nz divisible by 8)
    const int bid = blockIdx.x;
    const int z = (bid & 7) * (nz >> 3) + (bid >> 3);

    const int tile = z % 49;
    const int u = z / 49;
    const int b = u & 15;
    const int tc = u >> 4;

    const int ty = tile / 7, tx = tile - ty * 7;
    const int h0 = ty * 8, w0c = tx * 8;

    const int tid = threadIdx.x;

    // ---- stage x tile [64][10][10] into padded layout, +0.0f halo ----
    const float* xb = x + ((size_t)(b * T_N + (t0 + tc)) * CIN) * HWN;
    for (int i = tid; i < CIN * 100; i += 512) {
        int ci = i / 100;
        int rem = i - ci * 100;
        int rr = rem / 10;
        int cc = rem - rr * 10;
        int gh = h0 - 1 + rr;
        int gw = w0c - 1 + cc;
        float v = 0.0f;
        if ((unsigned)gh < (unsigned)HS && (unsigned)gw < (unsigned)HS)
            v = xb[(size_t)ci * HWN + gh * HS + gw];
        xs[ci * XSC + rr * XSW + cc] = v;
    }
    __syncthreads();

    const int lane = tid & 63;
    const int wv = __builtin_amdgcn_readfirstlane(tid >> 6);  // 0..7, uniform
    const int co0 = wv * 16;
    const int lh = lane >> 3;       // local row 0..7
    const int lw = lane & 7;        // local col 0..7

    float acc[16];
#pragma unroll
    for (int j = 0; j < 16; ++j) acc[j] = 0.0f;

    for (int kh = 0; kh < 3; ++kh) {
        for (int kw = 0; kw < 3; ++kw) {
            const int xoff = (lh + kh) * XSW + (lw + kw);
            // uniform weight base for this (tap, wave)
            const float* wk = wt4 + ((size_t)(kh * 3 + kw) * CIN) * COUT + co0;
#pragma unroll 4
            for (int ci = 0; ci < CIN; ++ci) {
                const float xv = xs[ci * XSC + xoff];   // 2-way banks: free
#pragma unroll
                for (int j = 0; j < 16; ++j) {
                    // wk[..] wave-uniform -> s_load; FMA: SGPR x VGPR + VGPR
                    acc[j] = fmaf(xv, wk[ci * COUT + j], acc[j]);
                }
            }
        }
    }

    // bias (separate rounded add) + store: lanes = consecutive px -> coalesced
    const int h = h0 + lh;
    const int wq = w0c + lw;
    const size_t obase = ((size_t)(tc * 16 + b) * COUT + co0) * HWN
                       + (size_t)h * HS + wq;
#pragma unroll
    for (int j = 0; j < 16; ++j) {
        obuf[obase + (size_t)j * HWN] = __fadd_rn(acc[j], bias[co0 + j]);
    }
}

// ---------- recurrence, strict fp32, in-kernel t-loop ----------
__global__ __launch_bounds__(256) void rec32(
    const float* __restrict__ cvbuf, const float* __restrict__ fcw,
    const float* __restrict__ fcb, float* __restrict__ stateD,
    unsigned* __restrict__ stateS, float* __restrict__ out,
    int t0, int nt, int doLoad, int doStore)
{
    const int idx = blockIdx.x * 256 + threadIdx.x;  // 16*128*784 sites
    const int pw = idx % 28;
    int tmp = idx / 28;
    const int ph = tmp % 28;
    tmp /= 28;
    const int co = tmp & 127;
    const int b = tmp >> 7;

    const size_t g = (size_t)idx;

    const float w0 = fcw[0], w1 = fcw[1], w2 = fcw[2], fb = fcb[0];

    float u[4], m3[4], s[4];
    if (doLoad) {
        unsigned sm = stateS[g];
#pragma unroll
        for (int p = 0; p < 4; ++p) {
            u[p] = stateD[(size_t)p * NSG + g];
            m3[p] = stateD[(size_t)(4 + p) * NSG + g];
            s[p] = (float)((sm >> p) & 1u);
        }
    } else {
#pragma unroll
        for (int p = 0; p < 4; ++p) { u[p] = 0.0f; m3[p] = 0.0f; s[p] = 0.0f; }
    }

    const int h0 = ph * 2, wc0 = pw * 2;

    for (int tc = 0; tc < nt; ++tc) {
        const size_t cbase = ((size_t)(tc * 16 + b) * COUT + co) * HWN
                           + (size_t)h0 * HS + wc0;
        const float cv[4] = {cvbuf[cbase], cvbuf[cbase + 1],
                             cvbuf[cbase + HS], cvbuf[cbase + HS + 1]};

#pragma unroll
        for (int p = 0; p < 4; ++p) {
            float e0 = __fadd_rn(__fadd_rn(__fmul_rn(u[p], w0), __fmul_rn(u[p], w1)),
                                 __fmul_rn(u[p], w2));
            float x4 = __fadd_rn(e0, fb);
            float dd = __fmul_rn(0.2f, __fsub_rn(1.0f, s[p]));
            u[p]  = __fadd_rn(__fmul_rn(u[p], dd), cv[p]);
            m3[p] = __fadd_rn(__fmul_rn(m3[p], dd), x4);
            float e1 = __fadd_rn(__fadd_rn(__fmul_rn(u[p], w0), __fmul_rn(u[p], w1)),
                                 __fmul_rn(u[p], w2));
            float mem1 = __fadd_rn(__fadd_rn(e1, fb), m3[p]);
            s[p] = (__fsub_rn(mem1, 0.8f) > 0.0f) ? 1.0f : 0.0f;
        }

        float pooled = 0.25f * (((s[0] + s[1]) + s[2]) + s[3]);
        out[(((size_t)b * T_N + (t0 + tc)) * COUT + co) * 784 + ph * 28 + pw] = pooled;
    }

    if (doStore) {
        unsigned sm = 0;
#pragma unroll
        for (int p = 0; p < 4; ++p) {
            stateD[(size_t)p * NSG + g] = u[p];
            stateD[(size_t)(4 + p) * NSG + g] = m3[p];
            sm |= (s[p] > 0.5f) ? (1u << p) : 0u;
        }
        stateS[g] = sm;
    }
}

extern "C" void kernel_launch(void* const* d_in, const int* in_sizes, int n_in,
                              void* d_out, int out_size, void* d_ws, size_t ws_size,
                              hipStream_t stream) {
    const float* x     = (const float*)d_in[0];
    const float* cw    = (const float*)d_in[1];
    const float* cbias = (const float*)d_in[2];
    const float* fcw   = (const float*)d_in[3];
    const float* fcb   = (const float*)d_in[4];
    float* out = (float*)d_out;

    const size_t wtB   = (size_t)576 * COUT * sizeof(float);        // 294 KB
    const size_t convT = (size_t)B_N * COUT * HWN * sizeof(float);  // 25.69 MB / t
    const size_t statB = (size_t)NSG * 8 * sizeof(float)
                       + (size_t)NSG * sizeof(unsigned);            // ~57.8 MB

    int Tc;
    if (wtB + (size_t)T_N * convT <= ws_size) {
        Tc = T_N;                                   // no state spill needed
    } else if (ws_size > wtB + statB + convT) {
        Tc = (int)((ws_size - wtB - statB) / convT);
        if (Tc > T_N) Tc = T_N;
    } else {
        return;  // ws unusably small
    }

    float* wt4 = (float*)d_ws;
    float* convbuf = (float*)((char*)d_ws + wtB);
    float* stateD = (float*)((char*)d_ws + wtB + (size_t)Tc * convT);
    unsigned* stateS = (unsigned*)((char*)stateD + (size_t)NSG * 8 * sizeof(float));

    wt_kernel<<<(COUT * 576 + 255) / 256, 256, 0, stream>>>(cw, wt4);

    for (int t0 = 0; t0 < T_N; t0 += Tc) {
        const int nt = (T_N - t0 < Tc) ? (T_N - t0) : Tc;
        const int nz = nt * 16 * 49;                // divisible by 8
        conv_sgpr<<<nz, 512, 0, stream>>>(x, wt4, cbias, convbuf, t0, nz);
        rec32<<<NSG / 256, 256, 0, stream>>>(
            convbuf, fcw, fcb, stateD, stateS, out,
            t0, nt, t0 > 0 ? 1 : 0, (t0 + nt) < T_N ? 1 : 0);
    }
}

// Round 16
// 1377.643 us; speedup vs baseline: 1.1177x; 1.1177x over previous
//
#include <hip/hip_runtime.h>

#define B_N 16
#define T_N 15
#define CIN 64
#define COUT 128
#define HS 56
#define HWN 3136
#define NSG (16 * 128 * 28 * 28)

// PROVEN reference model (R10/R14, absmax=0.0):
//   conv: per-output flat sequential FMA chain, k-order (kh, kw, ci-innermost),
//         bias as separate rounded add. fma(+/-0,w,acc)==acc bit-exact.
//   elementwise/scan: per-op rounding, no FMA.
// R15 lessons: SQ_LDS_BANK_CONFLICT here is benign 2-way aliasing (not the
// stall); stride-12 pad + unroll-4 only hurt occupancy. Reverted.
// This round: wave = 32-co slice (4 waves/block) -> 32 FMAs per ds_read
// (double FMA density per lgkm wait). Per-co chain order unchanged.

// ---------- weight transpose: w[co][ci][kh][kw] -> wt4[tap][ci][co]
__global__ void wt_kernel(const float* __restrict__ w, float* __restrict__ wt4) {
    int i = blockIdx.x * 256 + threadIdx.x;  // 0 .. 73727
    if (i >= COUT * 576) return;
    int co = i / 576;
    int r = i - co * 576;      // ci*9 + kh*3 + kw
    int ci = r / 9;
    int kk = r - ci * 9;       // kh*3+kw
    wt4[((size_t)kk * CIN + ci) * COUT + co] = w[i];
}

// ---------- conv: 4 waves x (64 px lanes x 32 co acc), weights in SGPR ----
__global__ __launch_bounds__(256) void conv_sgpr(
    const float* __restrict__ x, const float* __restrict__ wt4,
    const float* __restrict__ bias, float* __restrict__ obuf,
    int t0, int nz)
{
    __shared__ float xs[CIN * 100];   // [ci][10][10], zero halo

    // XCD-chunked swizzle (nz divisible by 8)
    const int bid = blockIdx.x;
    const int z = (bid & 7) * (nz >> 3) + (bid >> 3);

    const int tile = z % 49;
    const int u = z / 49;
    const int b = u & 15;
    const int tc = u >> 4;

    const int ty = tile / 7, tx = tile - ty * 7;
    const int h0 = ty * 8, w0c = tx * 8;

    const int tid = threadIdx.x;

    // ---- stage x tile [64][10][10], +0.0f padding ----
    const float* xb = x + ((size_t)(b * T_N + (t0 + tc)) * CIN) * HWN;
    for (int i = tid; i < CIN * 100; i += 256) {
        int ci = i / 100;
        int rem = i - ci * 100;
        int rr = rem / 10;
        int cc = rem - rr * 10;
        int gh = h0 - 1 + rr;
        int gw = w0c - 1 + cc;
        float v = 0.0f;
        if ((unsigned)gh < (unsigned)HS && (unsigned)gw < (unsigned)HS)
            v = xb[(size_t)ci * HWN + gh * HS + gw];
        xs[i] = v;
    }
    __syncthreads();

    const int lane = tid & 63;
    const int wv = __builtin_amdgcn_readfirstlane(tid >> 6);  // 0..3, uniform
    const int co0 = wv * 32;
    const int lh = lane >> 3;       // local row 0..7
    const int lw = lane & 7;        // local col 0..7

    float acc[32];
#pragma unroll
    for (int j = 0; j < 32; ++j) acc[j] = 0.0f;

    for (int kh = 0; kh < 3; ++kh) {
        for (int kw = 0; kw < 3; ++kw) {
            const int xoff = (lh + kh) * 10 + (lw + kw);
            // uniform weight base for this (tap, wave)
            const float* wk = wt4 + ((size_t)(kh * 3 + kw) * CIN) * COUT + co0;
#pragma unroll 2
            for (int ci = 0; ci < CIN; ++ci) {
                const float xv = xs[ci * 100 + xoff];   // per-lane LDS read
#pragma unroll
                for (int j = 0; j < 32; ++j) {
                    // wk[..] wave-uniform -> s_load; FMA: SGPR x VGPR + VGPR
                    acc[j] = fmaf(xv, wk[ci * COUT + j], acc[j]);
                }
            }
        }
    }

    // bias (separate rounded add) + store: lanes = consecutive px -> coalesced
    const int h = h0 + lh;
    const int wq = w0c + lw;
    const size_t obase = ((size_t)(tc * 16 + b) * COUT + co0) * HWN
                       + (size_t)h * HS + wq;
#pragma unroll
    for (int j = 0; j < 32; ++j) {
        obuf[obase + (size_t)j * HWN] = __fadd_rn(acc[j], bias[co0 + j]);
    }
}

// ---------- recurrence, strict fp32, in-kernel t-loop ----------
__global__ __launch_bounds__(256) void rec32(
    const float* __restrict__ cvbuf, const float* __restrict__ fcw,
    const float* __restrict__ fcb, float* __restrict__ stateD,
    unsigned* __restrict__ stateS, float* __restrict__ out,
    int t0, int nt, int doLoad, int doStore)
{
    const int idx = blockIdx.x * 256 + threadIdx.x;  // 16*128*784 sites
    const int pw = idx % 28;
    int tmp = idx / 28;
    const int ph = tmp % 28;
    tmp /= 28;
    const int co = tmp & 127;
    const int b = tmp >> 7;

    const size_t g = (size_t)idx;

    const float w0 = fcw[0], w1 = fcw[1], w2 = fcw[2], fb = fcb[0];

    float u[4], m3[4], s[4];
    if (doLoad) {
        unsigned sm = stateS[g];
#pragma unroll
        for (int p = 0; p < 4; ++p) {
            u[p] = stateD[(size_t)p * NSG + g];
            m3[p] = stateD[(size_t)(4 + p) * NSG + g];
            s[p] = (float)((sm >> p) & 1u);
        }
    } else {
#pragma unroll
        for (int p = 0; p < 4; ++p) { u[p] = 0.0f; m3[p] = 0.0f; s[p] = 0.0f; }
    }

    const int h0 = ph * 2, wc0 = pw * 2;

    for (int tc = 0; tc < nt; ++tc) {
        const size_t cbase = ((size_t)(tc * 16 + b) * COUT + co) * HWN
                           + (size_t)h0 * HS + wc0;
        const float cv[4] = {cvbuf[cbase], cvbuf[cbase + 1],
                             cvbuf[cbase + HS], cvbuf[cbase + HS + 1]};

#pragma unroll
        for (int p = 0; p < 4; ++p) {
            float e0 = __fadd_rn(__fadd_rn(__fmul_rn(u[p], w0), __fmul_rn(u[p], w1)),
                                 __fmul_rn(u[p], w2));
            float x4 = __fadd_rn(e0, fb);
            float dd = __fmul_rn(0.2f, __fsub_rn(1.0f, s[p]));
            u[p]  = __fadd_rn(__fmul_rn(u[p], dd), cv[p]);
            m3[p] = __fadd_rn(__fmul_rn(m3[p], dd), x4);
            float e1 = __fadd_rn(__fadd_rn(__fmul_rn(u[p], w0), __fmul_rn(u[p], w1)),
                                 __fmul_rn(u[p], w2));
            float mem1 = __fadd_rn(__fadd_rn(e1, fb), m3[p]);
            s[p] = (__fsub_rn(mem1, 0.8f) > 0.0f) ? 1.0f : 0.0f;
        }

        float pooled = 0.25f * (((s[0] + s[1]) + s[2]) + s[3]);
        out[(((size_t)b * T_N + (t0 + tc)) * COUT + co) * 784 + ph * 28 + pw] = pooled;
    }

    if (doStore) {
        unsigned sm = 0;
#pragma unroll
        for (int p = 0; p < 4; ++p) {
            stateD[(size_t)p * NSG + g] = u[p];
            stateD[(size_t)(4 + p) * NSG + g] = m3[p];
            sm |= (s[p] > 0.5f) ? (1u << p) : 0u;
        }
        stateS[g] = sm;
    }
}

extern "C" void kernel_launch(void* const* d_in, const int* in_sizes, int n_in,
                              void* d_out, int out_size, void* d_ws, size_t ws_size,
                              hipStream_t stream) {
    const float* x     = (const float*)d_in[0];
    const float* cw    = (const float*)d_in[1];
    const float* cbias = (const float*)d_in[2];
    const float* fcw   = (const float*)d_in[3];
    const float* fcb   = (const float*)d_in[4];
    float* out = (float*)d_out;

    const size_t wtB   = (size_t)576 * COUT * sizeof(float);        // 294 KB
    const size_t convT = (size_t)B_N * COUT * HWN * sizeof(float);  // 25.69 MB / t
    const size_t statB = (size_t)NSG * 8 * sizeof(float)
                       + (size_t)NSG * sizeof(unsigned);            // ~57.8 MB

    int Tc;
    if (wtB + (size_t)T_N * convT <= ws_size) {
        Tc = T_N;                                   // no state spill needed
    } else if (ws_size > wtB + statB + convT) {
        Tc = (int)((ws_size - wtB - statB) / convT);
        if (Tc > T_N) Tc = T_N;
    } else {
        return;  // ws unusably small
    }

    float* wt4 = (float*)d_ws;
    float* convbuf = (float*)((char*)d_ws + wtB);
    float* stateD = (float*)((char*)d_ws + wtB + (size_t)Tc * convT);
    unsigned* stateS = (unsigned*)((char*)stateD + (size_t)NSG * 8 * sizeof(float));

    wt_kernel<<<(COUT * 576 + 255) / 256, 256, 0, stream>>>(cw, wt4);

    for (int t0 = 0; t0 < T_N; t0 += Tc) {
        const int nt = (T_N - t0 < Tc) ? (T_N - t0) : Tc;
        const int nz = nt * 16 * 49;                // divisible by 8
        conv_sgpr<<<nz, 256, 0, stream>>>(x, wt4, cbias, convbuf, t0, nz);
        rec32<<<NSG / 256, 256, 0, stream>>>(
            convbuf, fcw, fcb, stateD, stateS, out,
            t0, nt, t0 > 0 ? 1 : 0, (t0 + nt) < T_N ? 1 : 0);
    }
}